// Round 1
// baseline (146.139 us; speedup 1.0000x reference)
//
#include <hip/hip_runtime.h>
#include <stdint.h>

#define BATCH 16
#define NPROP 16384
#define NGT   128
#define NSAMP 256
#define NFG   64
#define GCAP  512

// ---------- threefry2x32 block (key 0,1) ----------
__device__ __forceinline__ void thr_block(uint32_t c0, uint32_t c1,
                                          uint32_t* o0, uint32_t* o1) {
    const uint32_t k0 = 0u, k1 = 1u, ks2 = 0x1BD11BDBu; // 0^1^0x1BD11BDA
    uint32_t x0 = c0 + k0, x1 = c1 + k1;
#define RND(d) { x0 += x1; x1 = (x1 << d) | (x1 >> (32 - d)); x1 ^= x0; }
    RND(13) RND(15) RND(26) RND(6)   x0 += k1;  x1 += ks2 + 1u;
    RND(17) RND(29) RND(16) RND(24)  x0 += ks2; x1 += k0 + 2u;
    RND(13) RND(15) RND(26) RND(6)   x0 += k0;  x1 += k1 + 3u;
    RND(17) RND(29) RND(16) RND(24)  x0 += k1;  x1 += ks2 + 4u;
    RND(13) RND(15) RND(26) RND(6)   x0 += ks2; x1 += k0 + 5u;
#undef RND
    *o0 = x0; *o1 = x1;
}

__device__ __forceinline__ uint32_t thr_part_xor(uint32_t f) {
    uint32_t a, b; thr_block(0u, f, &a, &b);
    return a ^ b;
}

// packed u32: [31:9]=r mantissa (bits>>9), [8:7]=lab (2=pos,1=neg,0=ign), [6:0]=argmax
__global__ void __launch_bounds__(256) k_compute(
    const float* __restrict__ props, const float* __restrict__ gts,
    uint32_t* __restrict__ packed, uint32_t* __restrict__ ghist)
{
#pragma clang fp contract(off)
    const int b = blockIdx.y;
    const int n = blockIdx.x * 256 + threadIdx.x;
    __shared__ float4 g4[NGT];
    __shared__ float sag[NGT];
    if (threadIdx.x < NGT) {
        float4 g = ((const float4*)gts)[(size_t)b * NGT + threadIdx.x];
        g4[threadIdx.x] = g;
        sag[threadIdx.x] = (g.z - g.x) * (g.w - g.y);   // same arith as before, hoisted
    }
    __syncthreads();
    const float4 pb = ((const float4*)props)[(size_t)b * NPROP + n];
    const float ap = (pb.z - pb.x) * (pb.w - pb.y);
    float best = -1.0f; int bg = 0;
    #pragma unroll 4
    for (int i = 0; i < NGT; ++i) {
        const float4 gb = g4[i];
        float w = fmaxf(fminf(pb.z, gb.z) - fmaxf(pb.x, gb.x), 0.0f);
        float hh = fmaxf(fminf(pb.w, gb.w) - fmaxf(pb.y, gb.y), 0.0f);
        float inter = w * hh;
        float un = fmaxf(ap + sag[i] - inter, 1e-8f);
        float iou = inter / un;                        // IEEE f32 div = numpy bits
        if (iou > best) { best = iou; bg = i; }        // first-max = argmax
    }
    uint32_t lab = (best >= 0.5f) ? 2u : ((best < 0.1f) ? 1u : 0u);
    const uint32_t f = (uint32_t)b * NPROP + (uint32_t)n;
    uint32_t bits = thr_part_xor(f);
    packed[f] = ((bits >> 9) << 9) | (lab << 7) | (uint32_t)bg;

    // first-level radix histograms, bit-identical bucket fns to keyA/keyB windows:
    //   pos row0: keyA>>26 & 2047 == mant[22:12] == bits>>21
    //   neg row1: keyB>>25 & 2047 == f32bits(2+r)>>11 & 2047
    //   ign row2: keyB>>34 & 2047 == f32bits(r)>>20 & 2047
    float r = __uint_as_float(0x3F800000u | (bits >> 9)) - 1.0f;
    uint32_t row, bucket;
    if (lab == 2u)      { row = 0u; bucket = (bits >> 21) & 2047u; }
    else if (lab == 1u) { row = 1u; bucket = (__float_as_uint(2.0f + r) >> 11) & 2047u; }
    else                { row = 2u; bucket = (__float_as_uint(r) >> 20) & 2047u; }
    atomicAdd(&ghist[(size_t)b * 6144 + row * 2048 + bucket], 1u);
}

__device__ __forceinline__ float r_from_packed(uint32_t p) {
    return __uint_as_float(0x3F800000u | (p >> 9)) - 1.0f;
}

// phase-0 key: 23-bit r-mantissa, 14-bit inv-index tie-break (37 bits)
__device__ __forceinline__ uint64_t keyA(uint32_t p, uint32_t n) {
    return (((uint64_t)(p >> 9)) << 14) | (uint64_t)(16383u - n);
}
// prio class: 3 = fg-selected, 2 = negative, 1 = pos-not-selected, 0 = ignore
__device__ __forceinline__ uint32_t cls_of(uint32_t p, uint32_t n, uint64_t thrA) {
    uint32_t lab = (p >> 7) & 3u;
    if (lab == 2u) return (keyA(p, n) >= thrA) ? 3u : 1u;
    return (lab == 1u) ? 2u : 0u;
}
// phase-1 key: f32 prio bits << 14 | inv-index (45 bits). Exact jnp f32 prio.
__device__ __forceinline__ uint64_t keyB(uint32_t p, uint32_t n, uint64_t thrA) {
    float r = r_from_packed(p);
    float prio = (float)cls_of(p, n, thrA) + r;
    return (((uint64_t)__float_as_uint(prio)) << 14) | (uint64_t)(16383u - n);
}

__global__ void __launch_bounds__(1024) k_select(
    const float* __restrict__ props, const float* __restrict__ gts,
    const uint32_t* __restrict__ packed, const uint32_t* __restrict__ ghist,
    float* __restrict__ out)
{
#pragma clang fp contract(off)
    const int b = blockIdx.x;
    const int tid = threadIdx.x;
    __shared__ uint32_t h[3 * 2048];     // 24 KB preloaded first-level hists
    __shared__ uint32_t hist2[2048];     // 8 KB refinement (rare path)
    __shared__ uint64_t gat[GCAP];       // 4 KB
    __shared__ uint64_t sel_keys[NSAMP]; // 2 KB
    __shared__ uint32_t sh_pos, sh_neg, sel_cnt, gcnt;
    __shared__ uint32_t sh_dig, sh_k, sh_cnt_in, sh_bA, sh_adjSub;
    __shared__ uint64_t sh_thr;

    const uint32_t* pk = packed + (size_t)b * NPROP;

    if (tid == 0) { sh_pos = 0; sh_neg = 0; sel_cnt = 0; }
    __syncthreads();
    // load hists + derive class counts (replaces 64KB staging + count pass)
    {
        uint32_t cp = 0, cn = 0;
        #pragma unroll
        for (int i = 0; i < 6; i++) {
            int idx = tid + i * 1024;
            uint32_t v = ghist[(size_t)b * 6144 + idx];
            h[idx] = v;
            if (i < 2) cp += v;
            else if (i < 4) cn += v;
        }
        #pragma unroll
        for (int off = 32; off > 0; off >>= 1) {
            cp += __shfl_down(cp, off);
            cn += __shfl_down(cn, off);
        }
        if ((tid & 63) == 0) { atomicAdd(&sh_pos, cp); atomicAdd(&sh_neg, cn); }
    }
    __syncthreads();
    const uint32_t npos = sh_pos;
    const uint32_t c3 = (npos < NFG) ? npos : NFG;
    const uint32_t c2 = sh_neg;
    const uint32_t c1 = npos - c3;

    uint64_t thrA = 0, thrB = 0;
    for (int phase = (npos > NFG ? 0 : 1); phase < 2; ++phase) {
        uint32_t k; int shift; uint32_t clsStar = 0; const uint32_t* hrow;
        if (phase == 0) { k = NFG; shift = 26; hrow = h; }
        else {
            // boundary class from analytic class counts (bands are disjoint)
            if (NSAMP <= c3 + c2)           { clsStar = 2; k = NSAMP - c3;           shift = 25; hrow = h + 2048; }
            else if (NSAMP <= c3 + c2 + c1) { clsStar = 1; k = NSAMP - c3 - c2;      shift = 26; hrow = h; }
            else                            { clsStar = 0; k = NSAMP - c3 - c2 - c1; shift = 34; hrow = h + 4096; }
        }
        uint64_t prefix = 0, mask = 0;
        bool first = true;
        for (;;) {
            if (!first) {
                // rare deep refinement: rebuild finer hist by scanning packed
                hist2[tid] = 0; hist2[tid + 1024] = 0;
                __syncthreads();
                for (int i = 0; i < 16; i++) {
                    uint32_t n = (uint32_t)(tid + i * 1024);
                    uint32_t p = pk[n];
                    bool elig; uint64_t key;
                    if (phase == 0) { elig = (((p >> 7) & 3u) == 2u); key = keyA(p, n); }
                    else { elig = (cls_of(p, n, thrA) == clsStar); key = keyB(p, n, thrA); }
                    if (elig && ((key ^ prefix) & mask) == 0)
                        atomicAdd(&hist2[(uint32_t)(key >> shift) & 2047u], 1u);
                }
                __syncthreads();
            }
            // boundary locate: wave 0 hierarchical suffix scan over 2048 bins.
            // For phase1/clsStar==1 first level: pos hist counts ALL positives,
            // but the 64 selected FG occupy exactly sh_adjSub slots of bucket
            // sh_bA and all buckets above it -> subtract/zero to get class-1 counts.
            {
                const uint32_t* hsrc = first ? hrow : hist2;
                const bool adj = first && (phase == 1) && (clsStar == 1u);
                const uint32_t adjB = sh_bA, adjSub = sh_adjSub;
                if (tid < 64) {
                    const uint32_t lane = tid;
                    auto HV = [&](uint32_t d) -> uint32_t {
                        uint32_t v = hsrc[d];
                        if (adj) v = (d > adjB) ? 0u : (d == adjB ? v - adjSub : v);
                        return v;
                    };
                    uint32_t cs = 0;
                    if (lane < 32) {
                        const uint32_t base = lane * 64u;
                        #pragma unroll 8
                        for (uint32_t i = 0; i < 64; i++) cs += HV(base + i);
                    }
                    uint32_t s = cs;
                    #pragma unroll
                    for (int off = 1; off < 32; off <<= 1) {
                        uint32_t t = __shfl_down(s, off);
                        if (lane + off < 32) s += t;
                    }
                    uint32_t sExcl = s - cs;
                    bool cond = (lane < 32) && (sExcl < k) && (k <= s);
                    uint64_t ball = __ballot(cond);
                    uint32_t cstar = (uint32_t)(__ffsll((unsigned long long)ball) - 1);
                    uint32_t kc = __shfl(k - sExcl, (int)cstar);
                    uint32_t val = HV(cstar * 64u + lane);
                    uint32_t fi = val;
                    #pragma unroll
                    for (int off = 1; off < 64; off <<= 1) {
                        uint32_t t = __shfl_down(fi, off);
                        if (lane + off < 64) fi += t;
                    }
                    uint32_t fExcl = fi - val;
                    bool cond2 = (fExcl < kc) && (kc <= fi);
                    uint64_t ball2 = __ballot(cond2);
                    uint32_t bstar = (uint32_t)(__ffsll((unsigned long long)ball2) - 1);
                    if (lane == bstar) {
                        sh_dig = cstar * 64u + lane;
                        sh_k = kc - fExcl;
                        sh_cnt_in = val;
                    }
                }
            }
            __syncthreads();
            uint32_t dig = sh_dig, kk = sh_k, cnt = sh_cnt_in;
            // record phase-0 first-level bucket + #selected within it (for cls-1 adj)
            if (phase == 0 && first && tid == 0) { sh_bA = dig; sh_adjSub = kk; }
            prefix |= ((uint64_t)dig) << shift;
            mask   |= 2047ull << shift;
            if (cnt <= GCAP || shift == 0) {
                if (tid == 0) gcnt = 0;
                __syncthreads();
                for (int i = 0; i < 16; i++) {
                    uint32_t n = (uint32_t)(tid + i * 1024);
                    uint32_t p = pk[n];
                    bool elig; uint64_t key;
                    if (phase == 0) { elig = (((p >> 7) & 3u) == 2u); key = keyA(p, n); }
                    else { elig = (cls_of(p, n, thrA) == clsStar); key = keyB(p, n, thrA); }
                    if (elig && ((key ^ prefix) & mask) == 0) {
                        uint32_t s = atomicAdd(&gcnt, 1u);
                        if (s < GCAP) gat[s] = key;
                    }
                }
                __syncthreads();
                // rank-select kk-th largest among gathered (keys unique)
                uint32_t gc = (gcnt < GCAP) ? gcnt : GCAP;
                if (tid < (int)gc) {
                    uint64_t x = gat[tid];
                    uint32_t r = 0;
                    for (uint32_t j = 0; j < gc; j++) r += (gat[j] > x);
                    if (r == kk - 1) sh_thr = x;
                }
                __syncthreads();
                break;
            } else {
                k = kk;
                shift = (shift >= 11) ? shift - 11 : 0;
                first = false;
                __syncthreads();
            }
        }
        if (phase == 0) thrA = sh_thr; else thrB = sh_thr;
        __syncthreads();
    }

    // compact: exactly NSAMP keys >= thrB (unordered; keys unique)
    for (int i = 0; i < 16; i++) {
        uint32_t n = (uint32_t)(tid + i * 1024);
        uint64_t key = keyB(pk[n], n, thrA);
        if (key >= thrB) {
            uint32_t slot = atomicAdd(&sel_cnt, 1u);
            if (slot < NSAMP) sel_keys[slot] = key;
        }
    }
    __syncthreads();

    // rank-scatter: output row = count of greater keys (== desc sort position)
    if (tid < NSAMP) {
        uint64_t x = sel_keys[tid];
        uint32_t r = 0;
        for (int j = 0; j < NSAMP; j++) r += (sel_keys[j] > x);
        uint32_t n = 16383u - (uint32_t)(x & 0x3FFFu);
        uint32_t p = pk[n];
        uint32_t lab = (p >> 7) & 3u;
        uint32_t bg = p & 0x7Fu;
        const float4 pb = ((const float4*)props)[(size_t)b * NPROP + n];
        const float4 gb = ((const float4*)gts)[(size_t)b * NGT + bg];
        const size_t O_ROI = 0;
        const size_t O_LBL = (size_t)BATCH * NSAMP * 4;
        const size_t O_TGT = O_LBL + (size_t)BATCH * NSAMP;
        const size_t O_INW = O_TGT + (size_t)BATCH * NSAMP * 4;
        const size_t O_OUW = O_INW + (size_t)BATCH * NSAMP * 4;
        const size_t row = (size_t)b * NSAMP + r;
        out[O_ROI + row * 4 + 0] = pb.x;
        out[O_ROI + row * 4 + 1] = pb.y;
        out[O_ROI + row * 4 + 2] = pb.z;
        out[O_ROI + row * 4 + 3] = pb.w;
        const int isfg = (lab == 2u) ? 1 : 0;
        out[O_LBL + row] = isfg ? 1.0f : 0.0f;
        float rw  = pb.z - pb.x, rh = pb.w - pb.y;
        float gw  = gb.z - gb.x, gh = gb.w - gb.y;
        out[O_TGT + row * 4 + 0] = ((gb.x + gb.z) * 0.5f - (pb.x + pb.z) * 0.5f) / rw;
        out[O_TGT + row * 4 + 1] = ((gb.y + gb.w) * 0.5f - (pb.y + pb.w) * 0.5f) / rh;
        out[O_TGT + row * 4 + 2] = logf(gw / rw);
        out[O_TGT + row * 4 + 3] = logf(gh / rh);
        float wv = isfg ? 1.0f : 0.0f;
        for (int c = 0; c < 4; c++) {
            out[O_INW + row * 4 + c] = wv;
            out[O_OUW + row * 4 + c] = wv;
        }
    }
}

extern "C" void kernel_launch(void* const* d_in, const int* in_sizes, int n_in,
                              void* d_out, int out_size, void* d_ws, size_t ws_size,
                              hipStream_t stream) {
    (void)in_sizes; (void)n_in; (void)out_size; (void)ws_size;
    const float* props = (const float*)d_in[0];
    const float* gts   = (const float*)d_in[1];
    uint32_t* packed = (uint32_t*)d_ws;                  // 1 MB
    uint32_t* ghist  = packed + (size_t)BATCH * NPROP;   // 16*3*2048 u32 = 384 KB
    float* out = (float*)d_out;

    hipMemsetAsync(ghist, 0, (size_t)BATCH * 3 * 2048 * sizeof(uint32_t), stream);
    dim3 gridA(NPROP / 256, BATCH);
    k_compute<<<gridA, 256, 0, stream>>>(props, gts, packed, ghist);
    k_select<<<BATCH, 1024, 0, stream>>>(props, gts, packed, ghist, out);
}